// Round 10
// baseline (240.596 us; speedup 1.0000x reference)
//
#include <hip/hip_runtime.h>

// ---------------- constants ----------------
#define BATCH   64
#define LSIG    240000
#define WIN     400
#define SHIFT   160
#define NFR     1498        // 1 + (240000-400)/160
#define NMEL    80
#define NBIN    200
#define NF      8           // frames per block
#define MAXW    14          // max nonzero mel-bank width
#define SPECW   (NBIN + MAXW)   // 214

// S layout: [f][rp][t2*2], r-stride 44 floats (bank-quad spread, worst ~2-way)
#define SSTR    44
#define SFR     484                  // frame stride (11*44)
#define S_TOT   (NF * SFR)           // 3872
#define WIN_OFF  S_TOT               // win[400]   (live: load..stage1)
#define XSEG_OFF (S_TOT + WIN)       // xseg[1520] (live: load..stage1)
#define SPEC_OFF S_TOT               // spec[8*214=1712] aliases win+xseg (stage2..3)
#define LDS_TOT (S_TOT + WIN + 1520) // 5792 floats = 23168 B -> 7 blocks/CU

// ---------------- compile-time trig (f64 Taylor, exact quadrants) ----------------
constexpr double D_PI = 3.14159265358979323846264338327950288;
constexpr double tsin(double x){ double x2=x*x,t=x,s=x; for(int n=1;n<=13;++n){ t*=-x2/double((2*n)*(2*n+1)); s+=t;} return s; }
constexpr double tcos(double x){ double x2=x*x,t=1.0,s=1.0; for(int n=1;n<=13;++n){ t*=-x2/double((2*n-1)*(2*n)); s+=t;} return s; }
constexpr float cos400(int j){ int a=((j%400)+400)%400; int q=a/100, rem=a%100; double x=D_PI*(double)rem/200.0;
    double v = q==0? tcos(x) : q==1? -tsin(x) : q==2? -tcos(x) : tsin(x); return (float)v; }
constexpr float sin400(int j){ int a=((j%400)+400)%400; int q=a/100, rem=a%100; double x=D_PI*(double)rem/200.0;
    double v = q==0? tsin(x) : q==1? tcos(x) : q==2? -tsin(x) : -tcos(x); return (float)v; }

// stage-2 twiddles per u=(m5,rp): 2a radix-5 (t2b=1..4) for k1/k2, 2b radix-4 (t2a=1..3)
struct Tw3 {
    float v[55][32];
    constexpr Tw3() : v{} {
        for (int m5=0;m5<5;++m5) for (int rp=0;rp<11;++rp) {
            int u = m5*11+rp;
            int k1 = rp + 20*m5;
            int k2 = (20-rp) + 20*m5;
            for (int tb=1; tb<=4; ++tb) {
                v[u][2*(tb-1)]     =  cos400(4*k1*tb);
                v[u][2*(tb-1)+1]   = -sin400(4*k1*tb);
                v[u][8+2*(tb-1)]   =  cos400(4*k2*tb);
                v[u][8+2*(tb-1)+1] = -sin400(4*k2*tb);
            }
            for (int ta=1; ta<=3; ++ta) {
                v[u][16+2*(ta-1)]   =  cos400(k1*ta);
                v[u][16+2*(ta-1)+1] = -sin400(k1*ta);
                v[u][22+2*(ta-1)]   =  cos400(k2*ta);
                v[u][22+2*(ta-1)+1] = -sin400(k2*ta);
            }
        }
    }
};
__device__ const Tw3 g_tw3{};

// ---------------- stage-1: t1-outer, 22 accumulators, literal twiddles ----------------
template<int T1, int R> struct Mac1R {
    static __device__ __forceinline__ void go(float y, float* ar, float* ai) {
        constexpr int j = ((R * T1) % 20) * 20;
        constexpr float c =  cos400(j);
        constexpr float s = -sin400(j);
        if constexpr (c == 1.0f)       ar[R] += y;
        else if constexpr (c == -1.0f) ar[R] -= y;
        else if constexpr (c != 0.0f)  ar[R] = fmaf(y, c, ar[R]);
        if constexpr (s == 1.0f)       ai[R] += y;
        else if constexpr (s == -1.0f) ai[R] -= y;
        else if constexpr (s != 0.0f)  ai[R] = fmaf(y, s, ai[R]);
        Mac1R<T1, R + 1>::go(y, ar, ai);
    }
};
template<int T1> struct Mac1R<T1, 11> { static __device__ __forceinline__ void go(float, float*, float*) {} };

template<int T1> struct Col {
    static __device__ __forceinline__ void go(const float* xf, const float* winS, int t2,
                                              float* ar, float* ai) {
        int t = t2 + 20 * T1;
        int tp = t - 1;
        if constexpr (T1 == 0) tp = max(tp, 0);   // t==0: win==0 -> y=0 anyway
        float y = (xf[t] - 0.97f * xf[tp]) * winS[t];
        Mac1R<T1, 0>::go(y, ar, ai);
        Col<T1 + 1>::go(xf, winS, t2, ar, ai);
    }
};
template<> struct Col<20> { static __device__ __forceinline__ void go(const float*, const float*, int, float*, float*) {} };

// ---------------- main fbank kernel ----------------
__global__ __launch_bounds__(256, 7)
void fbank_kernel(const float* __restrict__ x, const float* __restrict__ norm,
                  float* __restrict__ out) {
    const int ft = blockIdx.x;
    const int b  = blockIdx.y;
    const int f0 = ft * NF;
    const int nf = min(NF, NFR - f0);
    const int tid = threadIdx.x;

    __shared__ __align__(16) float smem[LDS_TOT];
    float* Sb   = smem;
    float* winS = smem + WIN_OFF;
    float* xseg = smem + XSEG_OFF;
    float* spec = smem + SPEC_OFF;

    // global x -> LDS
    const float* xb = x + (size_t)b * LSIG + (size_t)f0 * SHIFT;
    const int seglen = (nf - 1) * SHIFT + WIN;
    for (int i = tid; i < seglen; i += 256) xseg[i] = xb[i];

    // Hann window in LDS (2 HW cos/thread; overlaps x-load latency)
    const float TWO_PI = 6.28318530717958647693f;
    for (int j = tid; j < WIN; j += 256)
        winS[j] = 0.5f - 0.5f * __cosf(TWO_PI * (float)j / 399.0f);
    __syncthreads();

    // ---- stage 1: preemph+window fused, literal-twiddle 20-pt real DFTs, t1-outer ----
    if (tid < nf * 20) {
        const int f = tid / 20, t2 = tid - f * 20;
        float ar[11], ai[11];
#pragma unroll
        for (int r = 0; r < 11; ++r) { ar[r] = 0.0f; ai[r] = 0.0f; }
        Col<0>::go(xseg + f * SHIFT, winS, t2, ar, ai);
        float* Sf = Sb + f * SFR + 2 * t2;
#pragma unroll
        for (int r = 0; r < 11; ++r)
            *(float2*)(Sf + r * SSTR) = make_float2(ar[r], ai[r]);
    }
    __syncthreads();

    // ---- stage 2: 3-stage combine (radix-5 then radix-4), 4 bins/thread/frame ----
    if (tid < 220) {
        const int fquad = tid / 55, u = tid - fquad * 55;
        const int m5 = u / 11, rp = u - m5 * 11;
        const int k1 = rp + 20 * m5;
        const int k2 = (20 - rp) + 20 * m5;
        const bool valid2 = (rp >= 1 && rp <= 9);

        // twiddles -> registers (7 float4 = 28 floats)
        const float4* tp4 = (const float4*)&g_tw3.v[u][0];
        float4 w0 = tp4[0], w1 = tp4[1], w2 = tp4[2], w3 = tp4[3];
        float4 w4 = tp4[4], w5 = tp4[5], w6 = tp4[6];
        float t1c[5], t1s[5], t2c[5], t2s[5];
        t1c[1]=w0.x; t1s[1]=w0.y; t1c[2]=w0.z; t1s[2]=w0.w;
        t1c[3]=w1.x; t1s[3]=w1.y; t1c[4]=w1.z; t1s[4]=w1.w;
        t2c[1]=w2.x; t2s[1]=w2.y; t2c[2]=w2.z; t2s[2]=w2.w;
        t2c[3]=w3.x; t2s[3]=w3.y; t2c[4]=w3.z; t2s[4]=w3.w;
        float b1c[4], b1s[4], b2c[4], b2s[4];
        b1c[1]=w4.x; b1s[1]=w4.y; b1c[2]=w4.z; b1s[2]=w4.w;
        b1c[3]=w5.x; b1s[3]=w5.y;
        b2c[1]=w5.z; b2s[1]=w5.w; b2c[2]=w6.x; b2s[2]=w6.y;
        b2c[3]=w6.z; b2s[3]=w6.w;

#pragma unroll
        for (int fi = 0; fi < 2; ++fi) {
            const int f = 2 * fquad + fi;
            if (f < nf) {
                const float* Sf = Sb + f * SFR + rp * SSTR;
                float4 v0 = *(const float4*)(Sf);
                float4 v1 = *(const float4*)(Sf + 4);
                float U1r[4], U1i[4], U2r[4], U2i[4];
                U1r[0]=v0.x; U1i[0]=v0.y; U2r[0]=v0.x; U2i[0]=-v0.y;
                U1r[1]=v0.z; U1i[1]=v0.w; U2r[1]=v0.z; U2i[1]=-v0.w;
                U1r[2]=v1.x; U1i[2]=v1.y; U2r[2]=v1.x; U2i[2]=-v1.y;
                U1r[3]=v1.z; U1i[3]=v1.w; U2r[3]=v1.z; U2i[3]=-v1.w;
#pragma unroll
                for (int q = 2; q < 10; ++q) {
                    float4 v = *(const float4*)(Sf + 4 * q);
                    const int tb = q >> 1;             // 1..4
                    const int ta = (q & 1) * 2;        // 0 or 2
                    float c = t1c[tb], s = t1s[tb], c2 = t2c[tb], s2 = t2s[tb];
                    U1r[ta]   = fmaf(c,  v.x, fmaf(-s,  v.y, U1r[ta]));
                    U1i[ta]   = fmaf(s,  v.x, fmaf( c,  v.y, U1i[ta]));
                    U2r[ta]   = fmaf(c2, v.x, fmaf( s2, v.y, U2r[ta]));
                    U2i[ta]   = fmaf(s2, v.x, fmaf(-c2, v.y, U2i[ta]));
                    U1r[ta+1] = fmaf(c,  v.z, fmaf(-s,  v.w, U1r[ta+1]));
                    U1i[ta+1] = fmaf(s,  v.z, fmaf( c,  v.w, U1i[ta+1]));
                    U2r[ta+1] = fmaf(c2, v.z, fmaf( s2, v.w, U2r[ta+1]));
                    U2i[ta+1] = fmaf(s2, v.z, fmaf(-c2, v.w, U2i[ta+1]));
                }
                // 2b, k1 family: bins k1 and k1+100 share products (x(-i)^t2a)
                {
                    float p1r = fmaf(b1c[1],U1r[1], -b1s[1]*U1i[1]);
                    float p1i = fmaf(b1s[1],U1r[1],  b1c[1]*U1i[1]);
                    float p2r = fmaf(b1c[2],U1r[2], -b1s[2]*U1i[2]);
                    float p2i = fmaf(b1s[2],U1r[2],  b1c[2]*U1i[2]);
                    float p3r = fmaf(b1c[3],U1r[3], -b1s[3]*U1i[3]);
                    float p3i = fmaf(b1s[3],U1r[3],  b1c[3]*U1i[3]);
                    float Xr = (U1r[0] + p1r) + (p2r + p3r);
                    float Xi = (U1i[0] + p1i) + (p2i + p3i);
                    float Yr = (U1r[0] + p1i) - (p2r + p3i);
                    float Yi = (U1i[0] - p1r) + (p3r - p2i);
                    spec[f * SPECW + k1]       = fmaf(Xr, Xr, Xi * Xi);
                    spec[f * SPECW + k1 + 100] = fmaf(Yr, Yr, Yi * Yi);
                }
                // 2b, k2 family (conjugated S path)
                {
                    float p1r = fmaf(b2c[1],U2r[1], -b2s[1]*U2i[1]);
                    float p1i = fmaf(b2s[1],U2r[1],  b2c[1]*U2i[1]);
                    float p2r = fmaf(b2c[2],U2r[2], -b2s[2]*U2i[2]);
                    float p2i = fmaf(b2s[2],U2r[2],  b2c[2]*U2i[2]);
                    float p3r = fmaf(b2c[3],U2r[3], -b2s[3]*U2i[3]);
                    float p3i = fmaf(b2s[3],U2r[3],  b2c[3]*U2i[3]);
                    float Xr = (U2r[0] + p1r) + (p2r + p3r);
                    float Xi = (U2i[0] + p1i) + (p2i + p3i);
                    float Yr = (U2r[0] + p1i) - (p2r + p3i);
                    float Yi = (U2i[0] - p1r) + (p3r - p2i);
                    if (valid2) {
                        spec[f * SPECW + k2]       = fmaf(Xr, Xr, Xi * Xi);
                        spec[f * SPECW + k2 + 100] = fmaf(Yr, Yr, Yi * Yi);
                    }
                }
            }
        }
    } else if (tid < 220 + MAXW) {
        const int kp = NBIN + (tid - 220);           // zero pad taps
#pragma unroll
        for (int f = 0; f < NF; ++f) spec[f * SPECW + kp] = 0.0f;
    }
    __syncthreads();

    // ---- stage 3: in-thread mel weights (f32 HW log/exp), 3 frames/thread ----
    if (tid < 240) {
        const int m = tid % 80;
        const int g = tid / 80;                      // 0..2
        const float mlow  = 1127.0f * __logf(1.0f + 20.0f / 700.0f);
        const float mhigh = 1127.0f * __logf(1.0f + 8000.0f / 700.0f);
        const float d     = (mhigh - mlow) * (1.0f / 81.0f);
        const float left  = mlow + (float)m * d;
        const float inv_d = 1.0f / d;
        float freq_left = 700.0f * (__expf(left * (1.0f / 1127.0f)) - 1.0f);
        int kstart = (int)floorf(freq_left * 0.025f) + 1;
        float w[MAXW];
#pragma unroll
        for (int j = 0; j < MAXW; j++) {
            float melk = 1127.0f * __logf(1.0f + (float)(kstart + j) * (40.0f / 700.0f));
            float up = (melk - left) * inv_d;
            float dn = 2.0f - up;
            w[j] = fmaxf(0.0f, fminf(up, dn));
        }
        const float nm = norm[m];
        for (int i = 0; i < 3; i++) {
            int f = g + 3 * i;
            if (f < nf) {
                const float* sp = spec + f * SPECW + kstart;
                float acc = 0.0f;
#pragma unroll
                for (int j = 0; j < MAXW; j++)
                    acc = fmaf(w[j], sp[j], acc);
                float mel = fmaxf(acc, 2.2204460492503131e-16f);
                out[((size_t)b * NFR + (f0 + f)) * NMEL + m] = __logf(mel) * nm;
            }
        }
    }
}

// ---------------- masked mean subtraction ----------------
__global__ __launch_bounds__(256)
void meansub_kernel(float* __restrict__ out, const int* __restrict__ T) {
    const int b = blockIdx.x;
    __shared__ float part[3][NMEL];
    __shared__ float meanSh[NMEL];
    __shared__ int maxSh;

    if (threadIdx.x < 64) {                      // parallel max over BATCH=64
        int v = T[threadIdx.x];
#pragma unroll
        for (int o = 32; o >= 1; o >>= 1) v = max(v, __shfl_xor(v, o, 64));
        if (threadIdx.x == 0) maxSh = v;
    }
    __syncthreads();
    float ds = (float)maxSh / (float)NMEL;       // f32, matches numpy
    int tb = (int)((float)T[b] / ds);            // trunc, matches astype(int32)

    const int q = threadIdx.x / NMEL;            // 0..2 active
    const int m = threadIdx.x - q * NMEL;
    float* pb = out + (size_t)b * NFR * NMEL;

    if (q < 3) {
        float s = 0.0f;
        for (int f = q; f < tb; f += 3) s += pb[(size_t)f * NMEL + m];
        part[q][m] = s;
    }
    __syncthreads();
    if (threadIdx.x < NMEL)
        meanSh[m] = (part[0][m] + part[1][m] + part[2][m]) / (float)max(tb, 1);
    __syncthreads();
    if (q < 3) {
        float mean = meanSh[m];
        for (int f = q; f < tb; f += 3) pb[(size_t)f * NMEL + m] -= mean;
    }
}

// ---------------- launcher ----------------
extern "C" void kernel_launch(void* const* d_in, const int* in_sizes, int n_in,
                              void* d_out, int out_size, void* d_ws, size_t ws_size,
                              hipStream_t stream) {
    const float* x    = (const float*)d_in[0];
    const int*   T    = (const int*)d_in[1];
    const float* norm = (const float*)d_in[2];
    float* out = (float*)d_out;

    dim3 grid((NFR + NF - 1) / NF, BATCH);
    fbank_kernel<<<grid, 256, 0, stream>>>(x, norm, out);

    meansub_kernel<<<BATCH, 256, 0, stream>>>(out, T);
}